// Round 10
// baseline (1334.288 us; speedup 1.0000x reference)
//
#include <hip/hip_runtime.h>

static constexpr int NBLD = 100000, NCOM = 10000, EBU = 400000, ECO = 80000;
static constexpr int EBT = EBU + NBLD;   // 500000 (with self loops)
static constexpr int ECT = ECO + NCOM;   //  90000

typedef _Float16 f16;
typedef _Float16 f16x2 __attribute__((ext_vector_type(2)));
typedef _Float16 f16x8 __attribute__((ext_vector_type(8)));
typedef float f32x4 __attribute__((ext_vector_type(4)));

// ---- workspace layout (bytes). Peak ~177 MB (< 190 proven-safe envelope). ----
static constexpr size_t OFF_X1H  = 0;              // [NB,512] f16
static constexpr size_t OFF_CXL  = 0;              // [NC,512] f16 (overlay)
static constexpr size_t OFF_CXR  = 10240000;       // [NC,512] f16
static constexpr size_t OFF_CX1  = 20480000;       // [NC,512] f16
static constexpr size_t OFF_CX2L = 30720000;       // [NC,128] f16
static constexpr size_t OFF_CX2R = 33280000;       // ends 35,840,000
static constexpr size_t OFF_X2   = 0;              // [NB,128] f32 overlay (X1H dead after b2)
static constexpr size_t OFF_XLH  = 102400000;      // [NB,128] f16 2-head xl; XL2 overlays
static constexpr size_t OFF_XRH  = 128000000;      // [NB,128] f16 2-head xr; XR2 overlays
static constexpr size_t OFF_XL2  = 102400000;      // [NB,128] f16 (overlay of XLH)
static constexpr size_t OFF_XR2  = 128000000;      // [NB,128] f16 (overlay of XRH)
// persistent small:
static constexpr size_t OFF_BF16 = 153600000;      // [NB,64] f16
static constexpr size_t OFF_CXF16= 166400000;      // [NC,128] f16
static constexpr size_t OFF_WM   = 168960000;      // [NB,2] f32
static constexpr size_t OFF_XL3  = 169760000;      // [NB,2] f32
static constexpr size_t OFF_XR3  = 170560000;      // [NB,2] f32
static constexpr size_t OFF_FAW  = 171360000;      // 8*128*192 f16 = 393,216
static constexpr size_t OFF_B1LT = 171753216;      // 512*192 f16 = 196,608
static constexpr size_t OFF_B1RT = 171949824;      // 512*192 f16
static constexpr size_t OFF_B2T  = 172146432;      // 256*512 f16 = 262,144 (L rows 0-127, R 128-255)
static constexpr size_t OFF_BOFF = 172408576;      // (NB+1) int
static constexpr size_t OFF_BCUR = 172808592;      // NB int
static constexpr size_t OFF_BSRC = 173208592;      // EBT int
static constexpr size_t OFF_COFF = 175208592;      // (NC+1) int
static constexpr size_t OFF_CCUR = 175248608;      // NC int
static constexpr size_t OFF_CSRC = 175288608;      // ECT int
static constexpr size_t OFF_SC1  = 175648608;      // 256 int (building scan)
static constexpr size_t OFF_SC2  = 175649632;      // 256 int
static constexpr size_t OFF_SC1C = 175650656;      // 256 int (community scan)
static constexpr size_t OFF_SC2C = 175651680;      // 256 int, ends 175,652,704
static constexpr size_t OFF_C1T  = 175700000;      // 1024*32 f16 = 65,536
static constexpr size_t OFF_C2T  = 175765536;      // 256*512 f16 = 262,144
static constexpr size_t OFF_CF16 = 176027680;      // [NC,32] f16 = 640,000
// end ~176,667,680

// LDS row pad: 36 f16 = 72 B = 18 dwords. gcd(18,32)=2 -> <=2-way bank aliasing
// (free, m136) vs pad 40 (20 dwords, gcd 4 -> 4-way). Also cuts LDS 43 -> 36.9 KB.
static constexpr int LP = 36;

// ================= small utils =================
__global__ void k_zerof(float* __restrict__ p, int n) {
  int i = blockIdx.x * blockDim.x + threadIdx.x;
  if (i < n) p[i] = 0.f;
}

// float4 -> 4x f16 convert (row-copy, coalesced both sides)
__global__ void k_cvt4(const float* __restrict__ a, f16* __restrict__ b, int n4) {
  int i = blockIdx.x * blockDim.x + threadIdx.x;
  if (i >= n4) return;
  float4 f = *(const float4*)(a + (size_t)i * 4);
  f16x2 h0; h0[0] = (f16)f.x; h0[1] = (f16)f.y;
  f16x2 h1; h1[0] = (f16)f.z; h1[1] = (f16)f.w;
  *(unsigned*)(b + (size_t)i * 4)     = __builtin_bit_cast(unsigned, h0);
  *(unsigned*)(b + (size_t)i * 4 + 2) = __builtin_bit_cast(unsigned, h1);
}

// all 9 weight transposes (f32 [K,N] -> f16 [N,K]) in ONE launch; blockIdx.y = segment.
__global__ void k_cvtall(const float* __restrict__ fa_w1,
                         const float* __restrict__ b1_wl, const float* __restrict__ b1_wr,
                         const float* __restrict__ b2_wl, const float* __restrict__ b2_wr,
                         const float* __restrict__ c1_wl, const float* __restrict__ c1_wr,
                         const float* __restrict__ c2_wl, const float* __restrict__ c2_wr,
                         f16* __restrict__ FAW, f16* __restrict__ B1LT, f16* __restrict__ B1RT,
                         f16* __restrict__ B2T, f16* __restrict__ C1T, f16* __restrict__ C2T) {
  int seg = blockIdx.y;
  const float* W; f16* T; int K, N;
  if (seg < 8)        { W = fa_w1 + (size_t)seg * 192 * 128; T = FAW + (size_t)seg * 128 * 192; K = 192; N = 128; }
  else if (seg == 8)  { W = b1_wl; T = B1LT; K = 192; N = 512; }
  else if (seg == 9)  { W = b1_wr; T = B1RT; K = 192; N = 512; }
  else if (seg == 10) { W = b2_wl; T = B2T;  K = 512; N = 128; }
  else if (seg == 11) { W = b2_wr; T = B2T + 128 * 512; K = 512; N = 128; }
  else if (seg == 12) { W = c1_wl; T = C1T;  K = 32;  N = 512; }
  else if (seg == 13) { W = c1_wr; T = C1T + 512 * 32; K = 32; N = 512; }
  else if (seg == 14) { W = c2_wl; T = C2T;  K = 512; N = 128; }
  else                { W = c2_wr; T = C2T + 128 * 512; K = 512; N = 128; }
  int i = blockIdx.x * blockDim.x + threadIdx.x;
  if (i >= K * N) return;
  int n = i / K, k = i - n * K;
  T[(size_t)n * K + k] = (f16)W[(size_t)k * N + n];
}

// ================= CSR build (both graphs merged per stage) =================
__global__ void k_zero2(int* __restrict__ a, int na, int* __restrict__ b, int nb) {
  int i = blockIdx.x * blockDim.x + threadIdx.x;
  if (i < na) a[i] = 0;
  else if (i - na < nb) b[i - na] = 0;
}

__global__ void k_count2(const int* __restrict__ bdst, const int* __restrict__ cdst,
                         int* __restrict__ bcnt, int* __restrict__ ccnt) {
  int e = blockIdx.x * blockDim.x + threadIdx.x;
  if (e < EBT) {
    int dst = (e < EBU) ? bdst[e] : (e - EBU);
    atomicAdd(&bcnt[dst], 1);
  } else {
    int e2 = e - EBT;
    if (e2 >= ECT) return;
    int dst = (e2 < ECO) ? cdst[e2] : (e2 - ECO);
    atomicAdd(&ccnt[dst], 1);
  }
}

// blockIdx.y: 0 = building, 1 = community (extra x-blocks no-op via guards)
__global__ void k_scan1g(const int* __restrict__ bcnt, const int* __restrict__ ccnt,
                         int* __restrict__ boff, int* __restrict__ coff,
                         int* __restrict__ bsum, int* __restrict__ csum) {
  const int* cnt = blockIdx.y ? ccnt : bcnt;
  int* off = blockIdx.y ? coff : boff;
  int* sum = blockIdx.y ? csum : bsum;
  int N = blockIdx.y ? NCOM : NBLD;
  __shared__ int sh[256];
  int tid = threadIdx.x;
  int base = blockIdx.x * 2048 + tid * 8;
  int c[8]; int s = 0;
#pragma unroll
  for (int j = 0; j < 8; ++j) { int i = base + j; c[j] = (i < N) ? cnt[i] : 0; s += c[j]; }
  sh[tid] = s; __syncthreads();
  int own = s;
  for (int o = 1; o < 256; o <<= 1) {
    int v = (tid >= o) ? sh[tid - o] : 0; __syncthreads();
    sh[tid] += v; __syncthreads();
  }
  int ex = sh[tid] - own;
#pragma unroll
  for (int j = 0; j < 8; ++j) { int i = base + j; if (i < N) off[i] = ex; ex += c[j]; }
  if (tid == 255) sum[blockIdx.x] = sh[255];
}

// blockIdx.x: 0 = building, 1 = community
__global__ void k_scan2g(const int* __restrict__ bsum, const int* __restrict__ csum,
                         int nb, int nc, int* __restrict__ bpre, int* __restrict__ cpre) {
  const int* sum = blockIdx.x ? csum : bsum;
  int n = blockIdx.x ? nc : nb;
  int* pre = blockIdx.x ? cpre : bpre;
  __shared__ int sh[256];
  int tid = threadIdx.x;
  int v0 = (tid < n) ? sum[tid] : 0;
  sh[tid] = v0; __syncthreads();
  for (int o = 1; o < 256; o <<= 1) {
    int v = (tid >= o) ? sh[tid - o] : 0; __syncthreads();
    sh[tid] += v; __syncthreads();
  }
  pre[tid] = sh[tid] - v0;
}

// scan3 with cur copy folded in
__global__ void k_scan3c(int* __restrict__ off, int N, const int* __restrict__ bpre, int Et,
                         int* __restrict__ cur) {
  int i = blockIdx.x * blockDim.x + threadIdx.x;
  if (i < N) {
    int v = off[i] + bpre[i >> 11];
    off[i] = v;
    cur[i] = v;
  }
  if (i == 0) off[N] = Et;
}

__global__ void k_scatter2(const int* __restrict__ bsrc, const int* __restrict__ bdst,
                           const int* __restrict__ csrc, const int* __restrict__ cdst,
                           int* __restrict__ bcur, int* __restrict__ ccur,
                           int* __restrict__ bout, int* __restrict__ cout) {
  int e = blockIdx.x * blockDim.x + threadIdx.x;
  if (e < EBT) {
    int s, d;
    if (e < EBU) { s = bsrc[e]; d = bdst[e]; } else { s = d = e - EBU; }
    bout[atomicAdd(&bcur[d], 1)] = s;
  } else {
    int e2 = e - EBT;
    if (e2 >= ECT) return;
    int s, d;
    if (e2 < ECO) { s = csrc[e2]; d = cdst[e2]; } else { s = d = e2 - ECO; }
    cout[atomicAdd(&ccur[d], 1)] = s;
  }
}

// ================= MFMA f16 GEMM building blocks =================
// Tile: BM=BN=128, BK=64 (two 32-sub-tiles, double LDS buffers, 36.9 KB).
// 4 waves (2x2), each wave 64x64 = 4x4 MFMA 16x16x32 per sub-tile (32 MFMA/phase).
// Pipeline: write regs->LDS, barrier, ISSUE next-64K loads, 32 MFMA (hides load
// latency), barrier. Row pad LP=36 -> <=2-way LDS bank aliasing on reads.
// C/D: col=lane&15, row=(lane>>4)*4+reg.

struct frag32 { f16x8 v0, v1; };   // 32 B / thread = one 128x32 sub-tile slice

static __device__ inline frag32 loadA_lin(const f16* __restrict__ X, int lda,
                                          int k0, int tid, int bm, int M) {
  int row = tid >> 1, half = tid & 1;
  int grow = bm + row;
  frag32 r; r.v0 = (f16x8){}; r.v1 = (f16x8){};
  if (grow < M) {
    const f16* p = X + (size_t)grow * lda + k0 + half * 16;
    r.v0 = *(const f16x8*)(p);
    r.v1 = *(const f16x8*)(p + 8);
  }
  return r;
}

// fused A (K=192): k<64 -> bf16h[grow]*s0, else cx16[mrow]*s1
template<bool SCALE>
static __device__ inline frag32 loadA_fused(const f16* __restrict__ bf16h,
                                            const f16* __restrict__ cx16, int mrow,
                                            f16 s0, f16 s1, int k0, int tid, int grow, int M) {
  int half = tid & 1;
  int gc = k0 + half * 16;
  frag32 r; r.v0 = (f16x8){}; r.v1 = (f16x8){};
  if (grow < M) {
    const f16* src; f16 s;
    if (gc < 64) { src = bf16h + (size_t)grow * 64 + gc; s = s0; }
    else         { src = cx16 + (size_t)mrow * 128 + (gc - 64); s = s1; }
    r.v0 = *(const f16x8*)(src);
    r.v1 = *(const f16x8*)(src + 8);
    if (SCALE) {
#pragma unroll
      for (int j = 0; j < 8; ++j) { r.v0[j] *= s; r.v1[j] *= s; }
    }
  }
  return r;
}

static __device__ inline frag32 loadB_T(const f16* __restrict__ WT, int ldk, int k0, int tid) {
  int col = tid >> 1, half = tid & 1;
  const f16* p = WT + (size_t)col * ldk + k0 + half * 16;
  frag32 r;
  r.v0 = *(const f16x8*)(p);
  r.v1 = *(const f16x8*)(p + 8);
  return r;
}

static __device__ inline frag32 loadB_Tpair(const f16* __restrict__ WLt, const f16* __restrict__ WRt,
                                            int ldk, int slab, int k0, int tid) {
  int col = tid >> 1, half = tid & 1;
  const f16* base = (col < 64) ? (WLt + (size_t)(slab + col) * ldk)
                               : (WRt + (size_t)(slab + col - 64) * ldk);
  const f16* p = base + k0 + half * 16;
  frag32 r;
  r.v0 = *(const f16x8*)(p);
  r.v1 = *(const f16x8*)(p + 8);
  return r;
}

static __device__ inline void writeFrag(f16 (*S)[LP], frag32 f, int tid) {
  int row = tid >> 1, half = tid & 1;
  *(f16x8*)&S[row][half * 16]     = f.v0;
  *(f16x8*)&S[row][half * 16 + 8] = f.v1;
}

static __device__ inline void mma_tiles(const f16 (*As)[LP], const f16 (*Bs)[LP],
                                        f32x4 acc[4][4], int wm, int wn, int lane) {
  int rl = lane & 15;
  int kg = (lane >> 4) * 8;
  f16x8 a[4], b[4];
#pragma unroll
  for (int i = 0; i < 4; ++i) a[i] = *(const f16x8*)&As[wm * 64 + i * 16 + rl][kg];
#pragma unroll
  for (int j = 0; j < 4; ++j) b[j] = *(const f16x8*)&Bs[wn * 64 + j * 16 + rl][kg];
#pragma unroll
  for (int i = 0; i < 4; ++i)
#pragma unroll
    for (int j = 0; j < 4; ++j)
      acc[i][j] = __builtin_amdgcn_mfma_f32_16x16x32_f16(a[i], b[j], acc[i][j], 0, 0, 0);
}

// ===== generic MFMA GEMM: A f16 [M,lda] x WT f16 [N,K] -> f16 out split at N0 =====
// 1-D XCD-swizzled grid: grid.x = 8*ppx*NCB, ppx = cdiv(cdiv(M,128),8).
template<int NCB>
__global__ __launch_bounds__(256) void k_mgemm_gen(
    const f16* __restrict__ A, int lda,
    const f16* __restrict__ WT, int K,
    f16* __restrict__ out0, f16* __restrict__ out1, int N0, int ldo, int M) {
  __shared__ f16 As[2][128][LP];
  __shared__ f16 Bs[2][128][LP];
  int tid = threadIdx.x;
  int ppx = gridDim.x / (8 * NCB);
  int xcd = blockIdx.x & 7;
  int j6 = blockIdx.x >> 3;
  int cb = j6 % NCB;
  int p = xcd * ppx + j6 / NCB;
  int bm = p * 128;
  if (bm >= M) return;
  int bn = cb * 128;
  int lane = tid & 63, w = tid >> 6, wm_ = w >> 1, wn = w & 1;
  f32x4 acc[4][4];
#pragma unroll
  for (int i = 0; i < 4; ++i)
#pragma unroll
    for (int j = 0; j < 4; ++j) acc[i][j] = (f32x4){0.f, 0.f, 0.f, 0.f};

  const f16* WTb = WT + (size_t)bn * K;
  int NT = K >> 5;
  frag32 a0 = loadA_lin(A, lda, 0, tid, bm, M);
  frag32 b0 = loadB_T(WTb, K, 0, tid);
  frag32 a1; a1.v0 = (f16x8){}; a1.v1 = (f16x8){};
  frag32 b1v = a1;
  if (NT > 1) { a1 = loadA_lin(A, lda, 32, tid, bm, M); b1v = loadB_T(WTb, K, 32, tid); }
  for (int t = 0; t < NT; t += 2) {
    writeFrag(As[0], a0, tid); writeFrag(Bs[0], b0, tid);
    bool two = (t + 1 < NT);
    if (two) { writeFrag(As[1], a1, tid); writeFrag(Bs[1], b1v, tid); }
    __syncthreads();
    if (t + 2 < NT) {
      a0 = loadA_lin(A, lda, (t + 2) * 32, tid, bm, M);
      b0 = loadB_T(WTb, K, (t + 2) * 32, tid);
      if (t + 3 < NT) {
        a1 = loadA_lin(A, lda, (t + 3) * 32, tid, bm, M);
        b1v = loadB_T(WTb, K, (t + 3) * 32, tid);
      }
    }
    mma_tiles(As[0], Bs[0], acc, wm_, wn, lane);
    if (two) mma_tiles(As[1], Bs[1], acc, wm_, wn, lane);
    __syncthreads();
  }
  int rbase = bm + wm_ * 64 + (lane >> 4) * 4;
  int cl = lane & 15;
#pragma unroll
  for (int mi = 0; mi < 4; ++mi)
#pragma unroll
    for (int ni = 0; ni < 4; ++ni) {
      int col = bn + wn * 64 + ni * 16 + cl;
      f16* o; int c;
      if (col < N0) { o = out0; c = col; } else { o = out1; c = col - N0; }
#pragma unroll
      for (int r = 0; r < 4; ++r) {
        int row = rbase + mi * 16 + r;
        if (row < M) o[(size_t)row * ldo + c] = (f16)acc[mi][ni][r];
      }
    }
}

// ===== b1 transform: fused A (192) x [b1wlT|b1wrT] head slab -> 2-head staging =====
// 1-D XCD-swizzled grid = 8*ppx*2; ch = head within the pair (col slab + colbase).
__global__ __launch_bounds__(256) void k_mgemm_b1(
    const f16* __restrict__ bf16h, const f16* __restrict__ cx16,
    const int* __restrict__ map, const float* __restrict__ wmv,
    const f16* __restrict__ WLt, const f16* __restrict__ WRt, int slabBase,
    f16* __restrict__ outl, f16* __restrict__ outr, int M) {
  __shared__ f16 As[2][128][LP];
  __shared__ f16 Bs[2][128][LP];
  int tid = threadIdx.x;
  int ppx = gridDim.x >> 4;
  int xcd = blockIdx.x & 7;
  int j6 = blockIdx.x >> 3;
  int ch = j6 & 1;
  int p = xcd * ppx + (j6 >> 1);
  int bm = p * 128;
  if (bm >= M) return;
  int slab = slabBase + ch * 64;
  int colbase = ch * 64;
  int lane = tid & 63, w = tid >> 6, wm_ = w >> 1, wn = w & 1;
  f32x4 acc[4][4];
#pragma unroll
  for (int i = 0; i < 4; ++i)
#pragma unroll
    for (int j = 0; j < 4; ++j) acc[i][j] = (f32x4){0.f, 0.f, 0.f, 0.f};

  int arow = bm + (tid >> 1);
  int mrow = 0; f16 s0 = (f16)1.f, s1 = (f16)1.f;
  if (arow < M) {
    mrow = map[arow];
    s0 = (f16)wmv[(size_t)arow * 2];
    s1 = (f16)wmv[(size_t)arow * 2 + 1];
  }

  frag32 a0 = loadA_fused<true>(bf16h, cx16, mrow, s0, s1, 0, tid, arow, M);
  frag32 b0 = loadB_Tpair(WLt, WRt, 192, slab, 0, tid);
  frag32 a1 = loadA_fused<true>(bf16h, cx16, mrow, s0, s1, 32, tid, arow, M);
  frag32 b1v = loadB_Tpair(WLt, WRt, 192, slab, 32, tid);
  for (int t = 0; t < 6; t += 2) {
    writeFrag(As[0], a0, tid); writeFrag(Bs[0], b0, tid);
    writeFrag(As[1], a1, tid); writeFrag(Bs[1], b1v, tid);
    __syncthreads();
    if (t + 2 < 6) {
      a0 = loadA_fused<true>(bf16h, cx16, mrow, s0, s1, (t + 2) * 32, tid, arow, M);
      b0 = loadB_Tpair(WLt, WRt, 192, slab, (t + 2) * 32, tid);
      a1 = loadA_fused<true>(bf16h, cx16, mrow, s0, s1, (t + 3) * 32, tid, arow, M);
      b1v = loadB_Tpair(WLt, WRt, 192, slab, (t + 3) * 32, tid);
    }
    mma_tiles(As[0], Bs[0], acc, wm_, wn, lane);
    mma_tiles(As[1], Bs[1], acc, wm_, wn, lane);
    __syncthreads();
  }
  int rbase = bm + wm_ * 64 + (lane >> 4) * 4;
  int cl = lane & 15;
#pragma unroll
  for (int mi = 0; mi < 4; ++mi)
#pragma unroll
    for (int ni = 0; ni < 4; ++ni) {
      int col = wn * 64 + ni * 16 + cl;
      f16* o = (col < 64) ? outl : outr;
      int c = colbase + (col & 63);
#pragma unroll
      for (int r = 0; r < 4; ++r) {
        int row = rbase + mi * 16 + r;
        if (row < M) o[(size_t)row * 128 + c] = (f16)acc[mi][ni][r];
      }
    }
}

// ===== feature-attention: fused-A16 x faw1T[h] + fused epilogue, XCD-swizzled =====
__global__ __launch_bounds__(256) void k_mgemm_fa(
    const f16* __restrict__ bf16h, const f16* __restrict__ cx16,
    const int* __restrict__ map,
    const f16* __restrict__ w1T, const float* __restrict__ b1,
    const float* __restrict__ w2, const float* __restrict__ b2,
    float* __restrict__ wmout, int M) {
  __shared__ f16 As[2][128][LP];
  __shared__ f16 Bs[2][128][LP];
  __shared__ float sred[128][4];
  int tid = threadIdx.x;
  int ppx = gridDim.x >> 6;
  int xcd = blockIdx.x & 7;
  int j6 = blockIdx.x >> 3;
  int p = xcd * ppx + (j6 >> 3);
  int h = j6 & 7;
  int bm = p * 128;
  if (bm >= M) return;
  int lane = tid & 63, w = tid >> 6, wm_ = w >> 1, wn = w & 1;
  f32x4 acc[4][4];
#pragma unroll
  for (int i = 0; i < 4; ++i)
#pragma unroll
    for (int j = 0; j < 4; ++j) acc[i][j] = (f32x4){0.f, 0.f, 0.f, 0.f};

  int arow = bm + (tid >> 1);
  int mrow = (arow < M) ? map[arow] : 0;
  const f16* WT = w1T + (size_t)h * 128 * 192;

  frag32 a0 = loadA_fused<false>(bf16h, cx16, mrow, (f16)1.f, (f16)1.f, 0, tid, arow, M);
  frag32 b0 = loadB_T(WT, 192, 0, tid);
  frag32 a1 = loadA_fused<false>(bf16h, cx16, mrow, (f16)1.f, (f16)1.f, 32, tid, arow, M);
  frag32 b1v = loadB_T(WT, 192, 32, tid);
  for (int t = 0; t < 6; t += 2) {
    writeFrag(As[0], a0, tid); writeFrag(Bs[0], b0, tid);
    writeFrag(As[1], a1, tid); writeFrag(Bs[1], b1v, tid);
    __syncthreads();
    if (t + 2 < 6) {
      a0 = loadA_fused<false>(bf16h, cx16, mrow, (f16)1.f, (f16)1.f, (t + 2) * 32, tid, arow, M);
      b0 = loadB_T(WT, 192, (t + 2) * 32, tid);
      a1 = loadA_fused<false>(bf16h, cx16, mrow, (f16)1.f, (f16)1.f, (t + 3) * 32, tid, arow, M);
      b1v = loadB_T(WT, 192, (t + 3) * 32, tid);
    }
    mma_tiles(As[0], Bs[0], acc, wm_, wn, lane);
    mma_tiles(As[1], Bs[1], acc, wm_, wn, lane);
    __syncthreads();
  }

  // epilogue: per-row s0 = sum_col relu(C+b1)*w20, s1 likewise; rows keyed by lane>>4.
  int cl = lane & 15;
#pragma unroll
  for (int mi = 0; mi < 4; ++mi) {
    float t0[4] = {0.f, 0.f, 0.f, 0.f}, t1[4] = {0.f, 0.f, 0.f, 0.f};
#pragma unroll
    for (int ni = 0; ni < 4; ++ni) {
      int col = wn * 64 + ni * 16 + cl;
      float b1c = b1[h * 128 + col];
      float w0c = w2[((size_t)h * 128 + col) * 2];
      float w1c = w2[((size_t)h * 128 + col) * 2 + 1];
#pragma unroll
      for (int r = 0; r < 4; ++r) {
        float hv = fmaxf(acc[mi][ni][r] + b1c, 0.f);
        t0[r] = fmaf(hv, w0c, t0[r]);
        t1[r] = fmaf(hv, w1c, t1[r]);
      }
    }
#pragma unroll
    for (int m = 1; m < 16; m <<= 1) {
#pragma unroll
      for (int r = 0; r < 4; ++r) { t0[r] += __shfl_xor(t0[r], m); t1[r] += __shfl_xor(t1[r], m); }
    }
    if (cl == 0) {
#pragma unroll
      for (int r = 0; r < 4; ++r) {
        int rib = wm_ * 64 + mi * 16 + (lane >> 4) * 4 + r;
        sred[rib][wn] = t0[r];
        sred[rib][2 + wn] = t1[r];
      }
    }
  }
  __syncthreads();
  if (tid < 128) {
    int grow = bm + tid;
    if (grow < M) {
      float l0 = sred[tid][0] + sred[tid][1] + b2[h * 2];
      float l1 = sred[tid][2] + sred[tid][3] + b2[h * 2 + 1];
      float mx = fmaxf(l0, l1);
      float e0 = __expf(l0 - mx), e1 = __expf(l1 - mx);
      float inv = 0.125f / (e0 + e1);
      atomicAdd(&wmout[(size_t)grow * 2], e0 * inv);
      atomicAdd(&wmout[(size_t)grow * 2 + 1], e1 * inv);
    }
  }
}

// ===== fused online-softmax GATv2 conv (CSR by dst, wave per node) =====
// 1-deep edge prefetch: next srcl + row load issued before current merge math.
template<int V, int G, bool RELU, typename IT, typename OT>
__global__ __launch_bounds__(256) void k_convf(const IT* __restrict__ xl, const IT* __restrict__ xr,
                                               const float* __restrict__ attw, const float* __restrict__ bias,
                                               const int* __restrict__ off, const int* __restrict__ srcl,
                                               OT* __restrict__ outp, int N, int ldx, int ldo) {
  int n = (int)((blockIdx.x * (unsigned)blockDim.x + threadIdx.x) >> 6);
  if (n >= N) return;
  int lane = threadIdx.x & 63;
  int base = lane * V;
  float xr_r[V], att_r[V], acc[V];
#pragma unroll
  for (int j = 0; j < V; ++j) {
    xr_r[j] = (float)xr[(size_t)n * ldx + base + j];
    att_r[j] = attw[base + j];
    acc[j] = 0.f;
  }
  float mh = -INFINITY, lh = 0.f;
  int p0 = off[n], p1 = off[n + 1];

  f16 rawn[V];
  auto ldrow = [&](int src, f16* dst) {
    if constexpr (V == 2 && sizeof(IT) == 2) {
      *(f16x2*)dst = *(const f16x2*)(&xl[(size_t)src * ldx + base]);
    } else if constexpr (V == 8 && sizeof(IT) == 2) {
      *(f16x8*)dst = *(const f16x8*)(&xl[(size_t)src * ldx + base]);
    } else {
#pragma unroll
      for (int j = 0; j < V; ++j) dst[j] = (f16)xl[(size_t)src * ldx + base + j];
    }
  };
  if (p0 < p1) ldrow(srcl[p0], rawn);
  for (int p = p0; p < p1; ++p) {
    f16 raw[V];
#pragma unroll
    for (int j = 0; j < V; ++j) raw[j] = rawn[j];
    if (p + 1 < p1) ldrow(srcl[p + 1], rawn);
    float xlv[V];
#pragma unroll
    for (int j = 0; j < V; ++j) xlv[j] = (float)raw[j];
    float part = 0.f;
#pragma unroll
    for (int j = 0; j < V; ++j) {
      float t = xlv[j] + xr_r[j];
      t = t > 0.f ? t : 0.2f * t;          // leaky_relu(., 0.2)
      part = fmaf(t, att_r[j], part);
    }
#pragma unroll
    for (int m = 1; m < G; m <<= 1) part += __shfl_xor(part, m);
    float mn = fmaxf(mh, part);
    float scl = __expf(mh - mn);
    float pe = __expf(part - mn);
    lh = lh * scl + pe;
#pragma unroll
    for (int j = 0; j < V; ++j) acc[j] = acc[j] * scl + pe * xlv[j];
    mh = mn;
  }
  float inv = 1.f / lh;
#pragma unroll
  for (int j = 0; j < V; ++j) {
    float v = fmaf(acc[j], inv, bias[base + j]);
    if (RELU) v = fmaxf(v, 0.f);
    outp[(size_t)n * ldo + base + j] = (OT)v;
  }
}

// ===== b3 transforms (wave per node) + fused conv3 + log_softmax =====
__global__ __launch_bounds__(256) void k_b3gemm(const float* __restrict__ x2, const float* __restrict__ wl,
                                                const float* __restrict__ wr,
                                                float* __restrict__ xl3, float* __restrict__ xr3, int NB) {
  int n = (int)((blockIdx.x * (unsigned)blockDim.x + threadIdx.x) >> 6);
  if (n >= NB) return;
  int lane = threadIdx.x & 63;
  float2 a = *(const float2*)(x2 + (size_t)n * 128 + lane * 2);
  float4 wlv = *(const float4*)(wl + lane * 4);
  float4 wrv = *(const float4*)(wr + lane * 4);
  float l0 = a.x * wlv.x + a.y * wlv.z;
  float l1 = a.x * wlv.y + a.y * wlv.w;
  float r0 = a.x * wrv.x + a.y * wrv.z;
  float r1 = a.x * wrv.y + a.y * wrv.w;
#pragma unroll
  for (int m = 1; m < 64; m <<= 1) {
    l0 += __shfl_xor(l0, m); l1 += __shfl_xor(l1, m);
    r0 += __shfl_xor(r0, m); r1 += __shfl_xor(r1, m);
  }
  if (lane == 0) {
    xl3[(size_t)n * 2] = l0; xl3[(size_t)n * 2 + 1] = l1;
    xr3[(size_t)n * 2] = r0; xr3[(size_t)n * 2 + 1] = r1;
  }
}

__global__ void k_conv3(const float* __restrict__ xl, const float* __restrict__ xr,
                        const float* __restrict__ att, const float* __restrict__ bias,
                        const int* __restrict__ off, const int* __restrict__ srcl,
                        float* __restrict__ out, int NB) {
  int n = blockIdx.x * blockDim.x + threadIdx.x;
  if (n >= NB) return;
  float a0 = att[0], a1 = att[1];
  float xr0 = xr[(size_t)n * 2], xr1 = xr[(size_t)n * 2 + 1];
  float mh = -INFINITY, lh = 0.f, c0 = 0.f, c1 = 0.f;
  int p0 = off[n], p1 = off[n + 1];
  float2 rawn = make_float2(0.f, 0.f);
  if (p0 < p1) rawn = *(const float2*)(xl + (size_t)srcl[p0] * 2);
  for (int p = p0; p < p1; ++p) {
    float sl0 = rawn.x, sl1 = rawn.y;
    if (p + 1 < p1) rawn = *(const float2*)(xl + (size_t)srcl[p + 1] * 2);
    float t0 = sl0 + xr0; t0 = t0 > 0.f ? t0 : 0.2f * t0;
    float t1 = sl1 + xr1; t1 = t1 > 0.f ? t1 : 0.2f * t1;
    float lg = t0 * a0 + t1 * a1;
    float mn = fmaxf(mh, lg);
    float scl = __expf(mh - mn);
    float pe = __expf(lg - mn);
    lh = lh * scl + pe;
    c0 = c0 * scl + pe * sl0;
    c1 = c1 * scl + pe * sl1;
    mh = mn;
  }
  float inv = 1.f / lh;
  float v0 = c0 * inv + bias[0];
  float v1 = c1 * inv + bias[1];
  float mx = fmaxf(v0, v1);
  float ls = mx + logf(__expf(v0 - mx) + __expf(v1 - mx));
  out[(size_t)n * 2] = v0 - ls;
  out[(size_t)n * 2 + 1] = v1 - ls;
}

static inline int cdiv(int a, int b) { return (a + b - 1) / b; }

extern "C" void kernel_launch(void* const* d_in, const int* in_sizes, int n_in,
                              void* d_out, int out_size, void* d_ws, size_t ws_size,
                              hipStream_t stream) {
  (void)in_sizes; (void)n_in; (void)out_size; (void)ws_size;
  const float* bfeat = (const float*)d_in[0];
  const float* cfeat = (const float*)d_in[1];
  const int* bei = (const int*)d_in[2];
  const int* cei = (const int*)d_in[3];
  const int* b2c = (const int*)d_in[4];
  const float* c1_wl = (const float*)d_in[5];
  const float* c1_wr = (const float*)d_in[6];
  const float* c1_att = (const float*)d_in[7];
  const float* c1_b = (const float*)d_in[8];
  const float* c2_wl = (const float*)d_in[9];
  const float* c2_wr = (const float*)d_in[10];
  const float* c2_att = (const float*)d_in[11];
  const float* c2_b = (const float*)d_in[12];
  const float* fa_w1 = (const float*)d_in[13];
  const float* fa_b1 = (const float*)d_in[14];
  const float* fa_w2 = (const float*)d_in[15];
  const float* fa_b2 = (const float*)d_in[16];
  const float* b1_wl = (const float*)d_in[17];
  const float* b1_wr = (const float*)d_in[18];
  const float* b1_att = (const float*)d_in[19];
  const float* b1_b = (const float*)d_in[20];
  const float* b2_wl = (const float*)d_in[21];
  const float* b2_wr = (const float*)d_in[22];
  const float* b2_att = (const float*)d_in[23];
  const float* b2_b = (const float*)d_in[24];
  const float* b3_wl = (const float*)d_in[25];
  const float* b3_wr = (const float*)d_in[26];
  const float* b3_att = (const float*)d_in[27];
  const float* b3_b = (const float*)d_in[28];
  char* ws = (char*)d_ws;
  float* out = (float*)d_out;

  const int* b_src_arr = bei;
  const int* b_dst_arr = bei + EBU;
  const int* c_src_arr = cei;
  const int* c_dst_arr = cei + ECO;

  f16*   X1H  = (f16*)(ws + OFF_X1H);
  float* X2   = (float*)(ws + OFF_X2);
  f16*   XLH  = (f16*)(ws + OFF_XLH);
  f16*   XRH  = (f16*)(ws + OFF_XRH);
  f16*   XL2  = (f16*)(ws + OFF_XL2);
  f16*   XR2  = (f16*)(ws + OFF_XR2);
  f16*   CXLh = (f16*)(ws + OFF_CXL);
  f16*   CXRh = (f16*)(ws + OFF_CXR);
  f16*   CX1h = (f16*)(ws + OFF_CX1);
  f16*   CX2Lh= (f16*)(ws + OFF_CX2L);
  f16*   CX2Rh= (f16*)(ws + OFF_CX2R);
  f16*   BF16 = (f16*)(ws + OFF_BF16);
  f16*   CXF16= (f16*)(ws + OFF_CXF16);
  float* WM   = (float*)(ws + OFF_WM);
  float* XL3  = (float*)(ws + OFF_XL3);
  float* XR3  = (float*)(ws + OFF_XR3);
  f16*   FAW  = (f16*)(ws + OFF_FAW);
  f16*   B1LT = (f16*)(ws + OFF_B1LT);
  f16*   B1RT = (f16*)(ws + OFF_B1RT);
  f16*   B2T  = (f16*)(ws + OFF_B2T);
  f16*   C1T  = (f16*)(ws + OFF_C1T);
  f16*   C2T  = (f16*)(ws + OFF_C2T);
  f16*   CF16 = (f16*)(ws + OFF_CF16);
  int* BOFF = (int*)(ws + OFF_BOFF);
  int* BCUR = (int*)(ws + OFF_BCUR);
  int* BSRC = (int*)(ws + OFF_BSRC);
  int* COFF = (int*)(ws + OFF_COFF);
  int* CCUR = (int*)(ws + OFF_CCUR);
  int* CSRC = (int*)(ws + OFF_CSRC);
  int* SC1  = (int*)(ws + OFF_SC1);
  int* SC2  = (int*)(ws + OFF_SC2);
  int* SC1C = (int*)(ws + OFF_SC1C);
  int* SC2C = (int*)(ws + OFF_SC2C);

  // ---- weight + feature f16 pre-conversion (one launch for all 9 weights) ----
  k_cvtall<<<dim3(cdiv(192 * 512, 256), 16), 256, 0, stream>>>(
      fa_w1, b1_wl, b1_wr, b2_wl, b2_wr, c1_wl, c1_wr, c2_wl, c2_wr,
      FAW, B1LT, B1RT, B2T, C1T, C2T);
  k_cvt4<<<cdiv(NBLD * 16, 256), 256, 0, stream>>>(bfeat, BF16, NBLD * 16);
  k_cvt4<<<cdiv(NCOM * 8, 256), 256, 0, stream>>>(cfeat, CF16, NCOM * 8);

  // ---- CSR build (both graphs, merged stages) ----
  k_zero2<<<cdiv(NBLD + NCOM, 256), 256, 0, stream>>>(BCUR, NBLD, CCUR, NCOM);
  k_count2<<<cdiv(EBT + ECT, 256), 256, 0, stream>>>(b_dst_arr, c_dst_arr, BCUR, CCUR);
  k_scan1g<<<dim3(cdiv(NBLD, 2048), 2), 256, 0, stream>>>(BCUR, CCUR, BOFF, COFF, SC1, SC1C);
  k_scan2g<<<2, 256, 0, stream>>>(SC1, SC1C, cdiv(NBLD, 2048), cdiv(NCOM, 2048), SC2, SC2C);
  k_scan3c<<<cdiv(NBLD, 256), 256, 0, stream>>>(BOFF, NBLD, SC2, EBT, BCUR);
  k_scan3c<<<cdiv(NCOM, 256), 256, 0, stream>>>(COFF, NCOM, SC2C, ECT, CCUR);
  k_scatter2<<<cdiv(EBT + ECT, 256), 256, 0, stream>>>(
      b_src_arr, b_dst_arr, c_src_arr, c_dst_arr, BCUR, CCUR, BSRC, CSRC);

  // ---- community GNN (MFMA f16) ----
  {
    int pC = cdiv(cdiv(NCOM, 128), 8);     // 10
    k_mgemm_gen<8><<<8 * pC * 8, 256, 0, stream>>>(
        CF16, 32, C1T, 32, CXLh, CXRh, 512, 512, NCOM);
    k_convf<8, 8, true, f16, f16><<<cdiv(NCOM, 4), 256, 0, stream>>>(
        CXLh, CXRh, c1_att, c1_b, COFF, CSRC, CX1h, NCOM, 512, 512);
    k_mgemm_gen<2><<<8 * pC * 2, 256, 0, stream>>>(
        CX1h, 512, C2T, 512, CX2Lh, CX2Rh, 128, 128, NCOM);
    k_convf<2, 16, true, f16, f16><<<cdiv(NCOM, 4), 256, 0, stream>>>(
        CX2Lh, CX2Rh, c2_att, c2_b, COFF, CSRC, CXF16, NCOM, 128, 128);
  }

  // ---- feature-attention fusion (MFMA GEMM per head, XCD-swizzled) ----
  k_zerof<<<cdiv(NBLD * 2, 256), 256, 0, stream>>>(WM, NBLD * 2);
  {
    int panels = cdiv(NBLD, 128);          // 782
    int ppx = cdiv(panels, 8);             // 98
    k_mgemm_fa<<<64 * ppx, 256, 0, stream>>>(
        BF16, CXF16, b2c, FAW, fa_b1, fa_w2, fa_b2, WM, NBLD);
  }

  // ---- building conv1: head pairs (1 merged GEMM launch per pair) -> X1H f16 ----
  {
    int pB = cdiv(cdiv(NBLD, 128), 8);     // 98
    for (int cp = 0; cp < 4; ++cp) {
      k_mgemm_b1<<<16 * pB, 256, 0, stream>>>(
          BF16, CXF16, b2c, WM, B1LT, B1RT, cp * 128, XLH, XRH, NBLD);
      k_convf<2, 32, true, f16, f16><<<cdiv(NBLD, 4), 256, 0, stream>>>(
          XLH, XRH, b1_att + cp * 128, b1_b + cp * 128, BOFF, BSRC, X1H + cp * 128, NBLD, 128, 512);
    }
    // ---- b2: single K=512 MFMA GEMM -> XL2/XR2 f16 ----
    k_mgemm_gen<2><<<8 * pB * 2, 256, 0, stream>>>(
        X1H, 512, B2T, 512, XL2, XR2, 128, 128, NBLD);
  }

  // ---- building conv2 (f16 in, f32 out; X2 overlays dead X1H) ----
  k_convf<2, 16, true, f16, float><<<cdiv(NBLD, 4), 256, 0, stream>>>(
      XL2, XR2, b2_att, b2_b, BOFF, BSRC, X2, NBLD, 128, 128);

  // ---- conv3 + log_softmax ----
  k_b3gemm<<<cdiv(NBLD, 4), 256, 0, stream>>>(X2, b3_wl, b3_wr, XL3, XR3, NBLD);
  k_conv3<<<cdiv(NBLD, 256), 256, 0, stream>>>(XL3, XR3, b3_att, b3_b, BOFF, BSRC, out, NBLD);
}

// Round 11
// 928.516 us; speedup vs baseline: 1.4370x; 1.4370x over previous
//
#include <hip/hip_runtime.h>

static constexpr int NBLD = 100000, NCOM = 10000, EBU = 400000, ECO = 80000;
static constexpr int EBT = EBU + NBLD;   // 500000 (with self loops)
static constexpr int ECT = ECO + NCOM;   //  90000

typedef _Float16 f16;
typedef _Float16 f16x2 __attribute__((ext_vector_type(2)));
typedef _Float16 f16x8 __attribute__((ext_vector_type(8)));
typedef float f32x4 __attribute__((ext_vector_type(4)));

// ---- workspace layout (bytes). Peak ~177 MB (< 190 proven-safe envelope). ----
static constexpr size_t OFF_X1H  = 0;              // [NB,512] f16
static constexpr size_t OFF_CXL  = 0;              // [NC,512] f16 (overlay)
static constexpr size_t OFF_CXR  = 10240000;       // [NC,512] f16
static constexpr size_t OFF_CX1  = 20480000;       // [NC,512] f16
static constexpr size_t OFF_CX2L = 30720000;       // [NC,128] f16
static constexpr size_t OFF_CX2R = 33280000;       // ends 35,840,000
static constexpr size_t OFF_X2   = 0;              // [NB,128] f32 overlay (X1H dead after b2)
static constexpr size_t OFF_XLH  = 102400000;      // [NB,128] f16 2-head xl; XL2 overlays
static constexpr size_t OFF_XRH  = 128000000;      // [NB,128] f16 2-head xr; XR2 overlays
static constexpr size_t OFF_XL2  = 102400000;      // [NB,128] f16 (overlay of XLH)
static constexpr size_t OFF_XR2  = 128000000;      // [NB,128] f16 (overlay of XRH)
// persistent small:
static constexpr size_t OFF_BF16 = 153600000;      // [NB,64] f16
static constexpr size_t OFF_CXF16= 166400000;      // [NC,128] f16
static constexpr size_t OFF_WM   = 168960000;      // [NB,2] f32
static constexpr size_t OFF_XL3  = 169760000;      // [NB,2] f32
static constexpr size_t OFF_XR3  = 170560000;      // [NB,2] f32
static constexpr size_t OFF_FAW  = 171360000;      // 8*128*192 f16 = 393,216
static constexpr size_t OFF_B1LT = 171753216;      // 512*192 f16 = 196,608
static constexpr size_t OFF_B1RT = 171949824;      // 512*192 f16
static constexpr size_t OFF_B2T  = 172146432;      // 256*512 f16 = 262,144 (L rows 0-127, R 128-255)
static constexpr size_t OFF_BOFF = 172408576;      // (NB+1) int
static constexpr size_t OFF_BCUR = 172808592;      // NB int
static constexpr size_t OFF_BSRC = 173208592;      // EBT int
static constexpr size_t OFF_COFF = 175208592;      // (NC+1) int
static constexpr size_t OFF_CCUR = 175248608;      // NC int
static constexpr size_t OFF_CSRC = 175288608;      // ECT int
static constexpr size_t OFF_SC1  = 175648608;      // 256 int (building scan)
static constexpr size_t OFF_SC2  = 175649632;      // 256 int
static constexpr size_t OFF_SC1C = 175650656;      // 256 int (community scan)
static constexpr size_t OFF_SC2C = 175651680;      // 256 int, ends 175,652,704
static constexpr size_t OFF_C1T  = 175700000;      // 1024*32 f16 = 65,536
static constexpr size_t OFF_C2T  = 175765536;      // 256*512 f16 = 262,144
static constexpr size_t OFF_CF16 = 176027680;      // [NC,32] f16 = 640,000
// end ~176,667,680

// LDS row pad: MUST be a multiple of 8 f16 (16 B) to keep ds_read/write_b128 —
// LP=36 (72 B rows) broke alignment and split every b128 into b64 pairs (r10:
// fa 103->251 us, MfmaUtil 6.3). LP=40's fragment reads are exactly 2-way bank
// aliased (free). Measured best: LP=40.
static constexpr int LP = 40;

// ================= small utils =================
__global__ void k_zerof(float* __restrict__ p, int n) {
  int i = blockIdx.x * blockDim.x + threadIdx.x;
  if (i < n) p[i] = 0.f;
}

// float4 -> 4x f16 convert (row-copy, coalesced both sides)
__global__ void k_cvt4(const float* __restrict__ a, f16* __restrict__ b, int n4) {
  int i = blockIdx.x * blockDim.x + threadIdx.x;
  if (i >= n4) return;
  float4 f = *(const float4*)(a + (size_t)i * 4);
  f16x2 h0; h0[0] = (f16)f.x; h0[1] = (f16)f.y;
  f16x2 h1; h1[0] = (f16)f.z; h1[1] = (f16)f.w;
  *(unsigned*)(b + (size_t)i * 4)     = __builtin_bit_cast(unsigned, h0);
  *(unsigned*)(b + (size_t)i * 4 + 2) = __builtin_bit_cast(unsigned, h1);
}

// all 9 weight transposes (f32 [K,N] -> f16 [N,K]) in ONE launch; blockIdx.y = segment.
__global__ void k_cvtall(const float* __restrict__ fa_w1,
                         const float* __restrict__ b1_wl, const float* __restrict__ b1_wr,
                         const float* __restrict__ b2_wl, const float* __restrict__ b2_wr,
                         const float* __restrict__ c1_wl, const float* __restrict__ c1_wr,
                         const float* __restrict__ c2_wl, const float* __restrict__ c2_wr,
                         f16* __restrict__ FAW, f16* __restrict__ B1LT, f16* __restrict__ B1RT,
                         f16* __restrict__ B2T, f16* __restrict__ C1T, f16* __restrict__ C2T) {
  int seg = blockIdx.y;
  const float* W; f16* T; int K, N;
  if (seg < 8)        { W = fa_w1 + (size_t)seg * 192 * 128; T = FAW + (size_t)seg * 128 * 192; K = 192; N = 128; }
  else if (seg == 8)  { W = b1_wl; T = B1LT; K = 192; N = 512; }
  else if (seg == 9)  { W = b1_wr; T = B1RT; K = 192; N = 512; }
  else if (seg == 10) { W = b2_wl; T = B2T;  K = 512; N = 128; }
  else if (seg == 11) { W = b2_wr; T = B2T + 128 * 512; K = 512; N = 128; }
  else if (seg == 12) { W = c1_wl; T = C1T;  K = 32;  N = 512; }
  else if (seg == 13) { W = c1_wr; T = C1T + 512 * 32; K = 32; N = 512; }
  else if (seg == 14) { W = c2_wl; T = C2T;  K = 512; N = 128; }
  else                { W = c2_wr; T = C2T + 128 * 512; K = 512; N = 128; }
  int i = blockIdx.x * blockDim.x + threadIdx.x;
  if (i >= K * N) return;
  int n = i / K, k = i - n * K;
  T[(size_t)n * K + k] = (f16)W[(size_t)k * N + n];
}

// ================= CSR build (both graphs merged per stage) =================
__global__ void k_zero2(int* __restrict__ a, int na, int* __restrict__ b, int nb) {
  int i = blockIdx.x * blockDim.x + threadIdx.x;
  if (i < na) a[i] = 0;
  else if (i - na < nb) b[i - na] = 0;
}

__global__ void k_count2(const int* __restrict__ bdst, const int* __restrict__ cdst,
                         int* __restrict__ bcnt, int* __restrict__ ccnt) {
  int e = blockIdx.x * blockDim.x + threadIdx.x;
  if (e < EBT) {
    int dst = (e < EBU) ? bdst[e] : (e - EBU);
    atomicAdd(&bcnt[dst], 1);
  } else {
    int e2 = e - EBT;
    if (e2 >= ECT) return;
    int dst = (e2 < ECO) ? cdst[e2] : (e2 - ECO);
    atomicAdd(&ccnt[dst], 1);
  }
}

// blockIdx.y: 0 = building, 1 = community (extra x-blocks no-op via guards)
__global__ void k_scan1g(const int* __restrict__ bcnt, const int* __restrict__ ccnt,
                         int* __restrict__ boff, int* __restrict__ coff,
                         int* __restrict__ bsum, int* __restrict__ csum) {
  const int* cnt = blockIdx.y ? ccnt : bcnt;
  int* off = blockIdx.y ? coff : boff;
  int* sum = blockIdx.y ? csum : bsum;
  int N = blockIdx.y ? NCOM : NBLD;
  __shared__ int sh[256];
  int tid = threadIdx.x;
  int base = blockIdx.x * 2048 + tid * 8;
  int c[8]; int s = 0;
#pragma unroll
  for (int j = 0; j < 8; ++j) { int i = base + j; c[j] = (i < N) ? cnt[i] : 0; s += c[j]; }
  sh[tid] = s; __syncthreads();
  int own = s;
  for (int o = 1; o < 256; o <<= 1) {
    int v = (tid >= o) ? sh[tid - o] : 0; __syncthreads();
    sh[tid] += v; __syncthreads();
  }
  int ex = sh[tid] - own;
#pragma unroll
  for (int j = 0; j < 8; ++j) { int i = base + j; if (i < N) off[i] = ex; ex += c[j]; }
  if (tid == 255) sum[blockIdx.x] = sh[255];
}

// blockIdx.x: 0 = building, 1 = community
__global__ void k_scan2g(const int* __restrict__ bsum, const int* __restrict__ csum,
                         int nb, int nc, int* __restrict__ bpre, int* __restrict__ cpre) {
  const int* sum = blockIdx.x ? csum : bsum;
  int n = blockIdx.x ? nc : nb;
  int* pre = blockIdx.x ? cpre : bpre;
  __shared__ int sh[256];
  int tid = threadIdx.x;
  int v0 = (tid < n) ? sum[tid] : 0;
  sh[tid] = v0; __syncthreads();
  for (int o = 1; o < 256; o <<= 1) {
    int v = (tid >= o) ? sh[tid - o] : 0; __syncthreads();
    sh[tid] += v; __syncthreads();
  }
  pre[tid] = sh[tid] - v0;
}

// scan3 with cur copy folded in
__global__ void k_scan3c(int* __restrict__ off, int N, const int* __restrict__ bpre, int Et,
                         int* __restrict__ cur) {
  int i = blockIdx.x * blockDim.x + threadIdx.x;
  if (i < N) {
    int v = off[i] + bpre[i >> 11];
    off[i] = v;
    cur[i] = v;
  }
  if (i == 0) off[N] = Et;
}

__global__ void k_scatter2(const int* __restrict__ bsrc, const int* __restrict__ bdst,
                           const int* __restrict__ csrc, const int* __restrict__ cdst,
                           int* __restrict__ bcur, int* __restrict__ ccur,
                           int* __restrict__ bout, int* __restrict__ cout) {
  int e = blockIdx.x * blockDim.x + threadIdx.x;
  if (e < EBT) {
    int s, d;
    if (e < EBU) { s = bsrc[e]; d = bdst[e]; } else { s = d = e - EBU; }
    bout[atomicAdd(&bcur[d], 1)] = s;
  } else {
    int e2 = e - EBT;
    if (e2 >= ECT) return;
    int s, d;
    if (e2 < ECO) { s = csrc[e2]; d = cdst[e2]; } else { s = d = e2 - ECO; }
    cout[atomicAdd(&ccur[d], 1)] = s;
  }
}

// ================= MFMA f16 GEMM building blocks =================
// Tile: BM=BN=128, BK=64 (two 32-sub-tiles, double LDS buffers, 43 KB).
// 4 waves (2x2), each wave 64x64 = 4x4 MFMA 16x16x32 per sub-tile (32 MFMA/phase).
// Pipeline: write regs->LDS, barrier, ISSUE next-64K loads, 32 MFMA (hides load
// latency), barrier. C/D: col=lane&15, row=(lane>>4)*4+reg.

struct frag32 { f16x8 v0, v1; };   // 32 B / thread = one 128x32 sub-tile slice

static __device__ inline frag32 loadA_lin(const f16* __restrict__ X, int lda,
                                          int k0, int tid, int bm, int M) {
  int row = tid >> 1, half = tid & 1;
  int grow = bm + row;
  frag32 r; r.v0 = (f16x8){}; r.v1 = (f16x8){};
  if (grow < M) {
    const f16* p = X + (size_t)grow * lda + k0 + half * 16;
    r.v0 = *(const f16x8*)(p);
    r.v1 = *(const f16x8*)(p + 8);
  }
  return r;
}

// fused A (K=192): k<64 -> bf16h[grow]*s0, else cx16[mrow]*s1
template<bool SCALE>
static __device__ inline frag32 loadA_fused(const f16* __restrict__ bf16h,
                                            const f16* __restrict__ cx16, int mrow,
                                            f16 s0, f16 s1, int k0, int tid, int grow, int M) {
  int half = tid & 1;
  int gc = k0 + half * 16;
  frag32 r; r.v0 = (f16x8){}; r.v1 = (f16x8){};
  if (grow < M) {
    const f16* src; f16 s;
    if (gc < 64) { src = bf16h + (size_t)grow * 64 + gc; s = s0; }
    else         { src = cx16 + (size_t)mrow * 128 + (gc - 64); s = s1; }
    r.v0 = *(const f16x8*)(src);
    r.v1 = *(const f16x8*)(src + 8);
    if (SCALE) {
#pragma unroll
      for (int j = 0; j < 8; ++j) { r.v0[j] *= s; r.v1[j] *= s; }
    }
  }
  return r;
}

static __device__ inline frag32 loadB_T(const f16* __restrict__ WT, int ldk, int k0, int tid) {
  int col = tid >> 1, half = tid & 1;
  const f16* p = WT + (size_t)col * ldk + k0 + half * 16;
  frag32 r;
  r.v0 = *(const f16x8*)(p);
  r.v1 = *(const f16x8*)(p + 8);
  return r;
}

static __device__ inline frag32 loadB_Tpair(const f16* __restrict__ WLt, const f16* __restrict__ WRt,
                                            int ldk, int slab, int k0, int tid) {
  int col = tid >> 1, half = tid & 1;
  const f16* base = (col < 64) ? (WLt + (size_t)(slab + col) * ldk)
                               : (WRt + (size_t)(slab + col - 64) * ldk);
  const f16* p = base + k0 + half * 16;
  frag32 r;
  r.v0 = *(const f16x8*)(p);
  r.v1 = *(const f16x8*)(p + 8);
  return r;
}

static __device__ inline void writeFrag(f16 (*S)[LP], frag32 f, int tid) {
  int row = tid >> 1, half = tid & 1;
  *(f16x8*)&S[row][half * 16]     = f.v0;
  *(f16x8*)&S[row][half * 16 + 8] = f.v1;
}

static __device__ inline void mma_tiles(const f16 (*As)[LP], const f16 (*Bs)[LP],
                                        f32x4 acc[4][4], int wm, int wn, int lane) {
  int rl = lane & 15;
  int kg = (lane >> 4) * 8;
  f16x8 a[4], b[4];
#pragma unroll
  for (int i = 0; i < 4; ++i) a[i] = *(const f16x8*)&As[wm * 64 + i * 16 + rl][kg];
#pragma unroll
  for (int j = 0; j < 4; ++j) b[j] = *(const f16x8*)&Bs[wn * 64 + j * 16 + rl][kg];
#pragma unroll
  for (int i = 0; i < 4; ++i)
#pragma unroll
    for (int j = 0; j < 4; ++j)
      acc[i][j] = __builtin_amdgcn_mfma_f32_16x16x32_f16(a[i], b[j], acc[i][j], 0, 0, 0);
}

// ===== generic MFMA GEMM: A f16 [M,lda] x WT f16 [N,K] -> f16 out split at N0 =====
// 1-D XCD-swizzled grid: grid.x = 8*ppx*NCB, ppx = cdiv(cdiv(M,128),8).
template<int NCB>
__global__ __launch_bounds__(256) void k_mgemm_gen(
    const f16* __restrict__ A, int lda,
    const f16* __restrict__ WT, int K,
    f16* __restrict__ out0, f16* __restrict__ out1, int N0, int ldo, int M) {
  __shared__ f16 As[2][128][LP];
  __shared__ f16 Bs[2][128][LP];
  int tid = threadIdx.x;
  int ppx = gridDim.x / (8 * NCB);
  int xcd = blockIdx.x & 7;
  int j6 = blockIdx.x >> 3;
  int cb = j6 % NCB;
  int p = xcd * ppx + j6 / NCB;
  int bm = p * 128;
  if (bm >= M) return;
  int bn = cb * 128;
  int lane = tid & 63, w = tid >> 6, wm_ = w >> 1, wn = w & 1;
  f32x4 acc[4][4];
#pragma unroll
  for (int i = 0; i < 4; ++i)
#pragma unroll
    for (int j = 0; j < 4; ++j) acc[i][j] = (f32x4){0.f, 0.f, 0.f, 0.f};

  const f16* WTb = WT + (size_t)bn * K;
  int NT = K >> 5;
  frag32 a0 = loadA_lin(A, lda, 0, tid, bm, M);
  frag32 b0 = loadB_T(WTb, K, 0, tid);
  frag32 a1; a1.v0 = (f16x8){}; a1.v1 = (f16x8){};
  frag32 b1v = a1;
  if (NT > 1) { a1 = loadA_lin(A, lda, 32, tid, bm, M); b1v = loadB_T(WTb, K, 32, tid); }
  for (int t = 0; t < NT; t += 2) {
    writeFrag(As[0], a0, tid); writeFrag(Bs[0], b0, tid);
    bool two = (t + 1 < NT);
    if (two) { writeFrag(As[1], a1, tid); writeFrag(Bs[1], b1v, tid); }
    __syncthreads();
    if (t + 2 < NT) {
      a0 = loadA_lin(A, lda, (t + 2) * 32, tid, bm, M);
      b0 = loadB_T(WTb, K, (t + 2) * 32, tid);
      if (t + 3 < NT) {
        a1 = loadA_lin(A, lda, (t + 3) * 32, tid, bm, M);
        b1v = loadB_T(WTb, K, (t + 3) * 32, tid);
      }
    }
    mma_tiles(As[0], Bs[0], acc, wm_, wn, lane);
    if (two) mma_tiles(As[1], Bs[1], acc, wm_, wn, lane);
    __syncthreads();
  }
  int rbase = bm + wm_ * 64 + (lane >> 4) * 4;
  int cl = lane & 15;
#pragma unroll
  for (int mi = 0; mi < 4; ++mi)
#pragma unroll
    for (int ni = 0; ni < 4; ++ni) {
      int col = bn + wn * 64 + ni * 16 + cl;
      f16* o; int c;
      if (col < N0) { o = out0; c = col; } else { o = out1; c = col - N0; }
#pragma unroll
      for (int r = 0; r < 4; ++r) {
        int row = rbase + mi * 16 + r;
        if (row < M) o[(size_t)row * ldo + c] = (f16)acc[mi][ni][r];
      }
    }
}

// ===== b1 transform: fused A (192) x [b1wlT|b1wrT] head slab -> 2-head staging =====
// 1-D XCD-swizzled grid = 8*ppx*2; ch = head within the pair (col slab + colbase).
__global__ __launch_bounds__(256) void k_mgemm_b1(
    const f16* __restrict__ bf16h, const f16* __restrict__ cx16,
    const int* __restrict__ map, const float* __restrict__ wmv,
    const f16* __restrict__ WLt, const f16* __restrict__ WRt, int slabBase,
    f16* __restrict__ outl, f16* __restrict__ outr, int M) {
  __shared__ f16 As[2][128][LP];
  __shared__ f16 Bs[2][128][LP];
  int tid = threadIdx.x;
  int ppx = gridDim.x >> 4;
  int xcd = blockIdx.x & 7;
  int j6 = blockIdx.x >> 3;
  int ch = j6 & 1;
  int p = xcd * ppx + (j6 >> 1);
  int bm = p * 128;
  if (bm >= M) return;
  int slab = slabBase + ch * 64;
  int colbase = ch * 64;
  int lane = tid & 63, w = tid >> 6, wm_ = w >> 1, wn = w & 1;
  f32x4 acc[4][4];
#pragma unroll
  for (int i = 0; i < 4; ++i)
#pragma unroll
    for (int j = 0; j < 4; ++j) acc[i][j] = (f32x4){0.f, 0.f, 0.f, 0.f};

  int arow = bm + (tid >> 1);
  int mrow = 0; f16 s0 = (f16)1.f, s1 = (f16)1.f;
  if (arow < M) {
    mrow = map[arow];
    s0 = (f16)wmv[(size_t)arow * 2];
    s1 = (f16)wmv[(size_t)arow * 2 + 1];
  }

  frag32 a0 = loadA_fused<true>(bf16h, cx16, mrow, s0, s1, 0, tid, arow, M);
  frag32 b0 = loadB_Tpair(WLt, WRt, 192, slab, 0, tid);
  frag32 a1 = loadA_fused<true>(bf16h, cx16, mrow, s0, s1, 32, tid, arow, M);
  frag32 b1v = loadB_Tpair(WLt, WRt, 192, slab, 32, tid);
  for (int t = 0; t < 6; t += 2) {
    writeFrag(As[0], a0, tid); writeFrag(Bs[0], b0, tid);
    writeFrag(As[1], a1, tid); writeFrag(Bs[1], b1v, tid);
    __syncthreads();
    if (t + 2 < 6) {
      a0 = loadA_fused<true>(bf16h, cx16, mrow, s0, s1, (t + 2) * 32, tid, arow, M);
      b0 = loadB_Tpair(WLt, WRt, 192, slab, (t + 2) * 32, tid);
      a1 = loadA_fused<true>(bf16h, cx16, mrow, s0, s1, (t + 3) * 32, tid, arow, M);
      b1v = loadB_Tpair(WLt, WRt, 192, slab, (t + 3) * 32, tid);
    }
    mma_tiles(As[0], Bs[0], acc, wm_, wn, lane);
    mma_tiles(As[1], Bs[1], acc, wm_, wn, lane);
    __syncthreads();
  }
  int rbase = bm + wm_ * 64 + (lane >> 4) * 4;
  int cl = lane & 15;
#pragma unroll
  for (int mi = 0; mi < 4; ++mi)
#pragma unroll
    for (int ni = 0; ni < 4; ++ni) {
      int col = wn * 64 + ni * 16 + cl;
      f16* o = (col < 64) ? outl : outr;
      int c = colbase + (col & 63);
#pragma unroll
      for (int r = 0; r < 4; ++r) {
        int row = rbase + mi * 16 + r;
        if (row < M) o[(size_t)row * 128 + c] = (f16)acc[mi][ni][r];
      }
    }
}

// ===== feature-attention: fused-A16 x faw1T[h] + fused epilogue, XCD-swizzled =====
__global__ __launch_bounds__(256) void k_mgemm_fa(
    const f16* __restrict__ bf16h, const f16* __restrict__ cx16,
    const int* __restrict__ map,
    const f16* __restrict__ w1T, const float* __restrict__ b1,
    const float* __restrict__ w2, const float* __restrict__ b2,
    float* __restrict__ wmout, int M) {
  __shared__ f16 As[2][128][LP];
  __shared__ f16 Bs[2][128][LP];
  __shared__ float sred[128][4];
  int tid = threadIdx.x;
  int ppx = gridDim.x >> 6;
  int xcd = blockIdx.x & 7;
  int j6 = blockIdx.x >> 3;
  int p = xcd * ppx + (j6 >> 3);
  int h = j6 & 7;
  int bm = p * 128;
  if (bm >= M) return;
  int lane = tid & 63, w = tid >> 6, wm_ = w >> 1, wn = w & 1;
  f32x4 acc[4][4];
#pragma unroll
  for (int i = 0; i < 4; ++i)
#pragma unroll
    for (int j = 0; j < 4; ++j) acc[i][j] = (f32x4){0.f, 0.f, 0.f, 0.f};

  int arow = bm + (tid >> 1);
  int mrow = (arow < M) ? map[arow] : 0;
  const f16* WT = w1T + (size_t)h * 128 * 192;

  frag32 a0 = loadA_fused<false>(bf16h, cx16, mrow, (f16)1.f, (f16)1.f, 0, tid, arow, M);
  frag32 b0 = loadB_T(WT, 192, 0, tid);
  frag32 a1 = loadA_fused<false>(bf16h, cx16, mrow, (f16)1.f, (f16)1.f, 32, tid, arow, M);
  frag32 b1v = loadB_T(WT, 192, 32, tid);
  for (int t = 0; t < 6; t += 2) {
    writeFrag(As[0], a0, tid); writeFrag(Bs[0], b0, tid);
    writeFrag(As[1], a1, tid); writeFrag(Bs[1], b1v, tid);
    __syncthreads();
    if (t + 2 < 6) {
      a0 = loadA_fused<false>(bf16h, cx16, mrow, (f16)1.f, (f16)1.f, (t + 2) * 32, tid, arow, M);
      b0 = loadB_T(WT, 192, (t + 2) * 32, tid);
      a1 = loadA_fused<false>(bf16h, cx16, mrow, (f16)1.f, (f16)1.f, (t + 3) * 32, tid, arow, M);
      b1v = loadB_T(WT, 192, (t + 3) * 32, tid);
    }
    mma_tiles(As[0], Bs[0], acc, wm_, wn, lane);
    mma_tiles(As[1], Bs[1], acc, wm_, wn, lane);
    __syncthreads();
  }

  // epilogue: per-row s0 = sum_col relu(C+b1)*w20, s1 likewise; rows keyed by lane>>4.
  int cl = lane & 15;
#pragma unroll
  for (int mi = 0; mi < 4; ++mi) {
    float t0[4] = {0.f, 0.f, 0.f, 0.f}, t1[4] = {0.f, 0.f, 0.f, 0.f};
#pragma unroll
    for (int ni = 0; ni < 4; ++ni) {
      int col = wn * 64 + ni * 16 + cl;
      float b1c = b1[h * 128 + col];
      float w0c = w2[((size_t)h * 128 + col) * 2];
      float w1c = w2[((size_t)h * 128 + col) * 2 + 1];
#pragma unroll
      for (int r = 0; r < 4; ++r) {
        float hv = fmaxf(acc[mi][ni][r] + b1c, 0.f);
        t0[r] = fmaf(hv, w0c, t0[r]);
        t1[r] = fmaf(hv, w1c, t1[r]);
      }
    }
#pragma unroll
    for (int m = 1; m < 16; m <<= 1) {
#pragma unroll
      for (int r = 0; r < 4; ++r) { t0[r] += __shfl_xor(t0[r], m); t1[r] += __shfl_xor(t1[r], m); }
    }
    if (cl == 0) {
#pragma unroll
      for (int r = 0; r < 4; ++r) {
        int rib = wm_ * 64 + mi * 16 + (lane >> 4) * 4 + r;
        sred[rib][wn] = t0[r];
        sred[rib][2 + wn] = t1[r];
      }
    }
  }
  __syncthreads();
  if (tid < 128) {
    int grow = bm + tid;
    if (grow < M) {
      float l0 = sred[tid][0] + sred[tid][1] + b2[h * 2];
      float l1 = sred[tid][2] + sred[tid][3] + b2[h * 2 + 1];
      float mx = fmaxf(l0, l1);
      float e0 = __expf(l0 - mx), e1 = __expf(l1 - mx);
      float inv = 0.125f / (e0 + e1);
      atomicAdd(&wmout[(size_t)grow * 2], e0 * inv);
      atomicAdd(&wmout[(size_t)grow * 2 + 1], e1 * inv);
    }
  }
}

// ===== fused online-softmax GATv2 conv (CSR by dst, wave per node) =====
// 1-deep edge prefetch: next srcl + row load issued before current merge math.
template<int V, int G, bool RELU, typename IT, typename OT>
__global__ __launch_bounds__(256) void k_convf(const IT* __restrict__ xl, const IT* __restrict__ xr,
                                               const float* __restrict__ attw, const float* __restrict__ bias,
                                               const int* __restrict__ off, const int* __restrict__ srcl,
                                               OT* __restrict__ outp, int N, int ldx, int ldo) {
  int n = (int)((blockIdx.x * (unsigned)blockDim.x + threadIdx.x) >> 6);
  if (n >= N) return;
  int lane = threadIdx.x & 63;
  int base = lane * V;
  float xr_r[V], att_r[V], acc[V];
#pragma unroll
  for (int j = 0; j < V; ++j) {
    xr_r[j] = (float)xr[(size_t)n * ldx + base + j];
    att_r[j] = attw[base + j];
    acc[j] = 0.f;
  }
  float mh = -INFINITY, lh = 0.f;
  int p0 = off[n], p1 = off[n + 1];

  f16 rawn[V];
  auto ldrow = [&](int src, f16* dst) {
    if constexpr (V == 2 && sizeof(IT) == 2) {
      *(f16x2*)dst = *(const f16x2*)(&xl[(size_t)src * ldx + base]);
    } else if constexpr (V == 8 && sizeof(IT) == 2) {
      *(f16x8*)dst = *(const f16x8*)(&xl[(size_t)src * ldx + base]);
    } else {
#pragma unroll
      for (int j = 0; j < V; ++j) dst[j] = (f16)xl[(size_t)src * ldx + base + j];
    }
  };
  if (p0 < p1) ldrow(srcl[p0], rawn);
  for (int p = p0; p < p1; ++p) {
    f16 raw[V];
#pragma unroll
    for (int j = 0; j < V; ++j) raw[j] = rawn[j];
    if (p + 1 < p1) ldrow(srcl[p + 1], rawn);
    float xlv[V];
#pragma unroll
    for (int j = 0; j < V; ++j) xlv[j] = (float)raw[j];
    float part = 0.f;
#pragma unroll
    for (int j = 0; j < V; ++j) {
      float t = xlv[j] + xr_r[j];
      t = t > 0.f ? t : 0.2f * t;          // leaky_relu(., 0.2)
      part = fmaf(t, att_r[j], part);
    }
#pragma unroll
    for (int m = 1; m < G; m <<= 1) part += __shfl_xor(part, m);
    float mn = fmaxf(mh, part);
    float scl = __expf(mh - mn);
    float pe = __expf(part - mn);
    lh = lh * scl + pe;
#pragma unroll
    for (int j = 0; j < V; ++j) acc[j] = acc[j] * scl + pe * xlv[j];
    mh = mn;
  }
  float inv = 1.f / lh;
#pragma unroll
  for (int j = 0; j < V; ++j) {
    float v = fmaf(acc[j], inv, bias[base + j]);
    if (RELU) v = fmaxf(v, 0.f);
    outp[(size_t)n * ldo + base + j] = (OT)v;
  }
}

// ===== b3 transforms (wave per node) + fused conv3 + log_softmax =====
__global__ __launch_bounds__(256) void k_b3gemm(const float* __restrict__ x2, const float* __restrict__ wl,
                                                const float* __restrict__ wr,
                                                float* __restrict__ xl3, float* __restrict__ xr3, int NB) {
  int n = (int)((blockIdx.x * (unsigned)blockDim.x + threadIdx.x) >> 6);
  if (n >= NB) return;
  int lane = threadIdx.x & 63;
  float2 a = *(const float2*)(x2 + (size_t)n * 128 + lane * 2);
  float4 wlv = *(const float4*)(wl + lane * 4);
  float4 wrv = *(const float4*)(wr + lane * 4);
  float l0 = a.x * wlv.x + a.y * wlv.z;
  float l1 = a.x * wlv.y + a.y * wlv.w;
  float r0 = a.x * wrv.x + a.y * wrv.z;
  float r1 = a.x * wrv.y + a.y * wrv.w;
#pragma unroll
  for (int m = 1; m < 64; m <<= 1) {
    l0 += __shfl_xor(l0, m); l1 += __shfl_xor(l1, m);
    r0 += __shfl_xor(r0, m); r1 += __shfl_xor(r1, m);
  }
  if (lane == 0) {
    xl3[(size_t)n * 2] = l0; xl3[(size_t)n * 2 + 1] = l1;
    xr3[(size_t)n * 2] = r0; xr3[(size_t)n * 2 + 1] = r1;
  }
}

__global__ void k_conv3(const float* __restrict__ xl, const float* __restrict__ xr,
                        const float* __restrict__ att, const float* __restrict__ bias,
                        const int* __restrict__ off, const int* __restrict__ srcl,
                        float* __restrict__ out, int NB) {
  int n = blockIdx.x * blockDim.x + threadIdx.x;
  if (n >= NB) return;
  float a0 = att[0], a1 = att[1];
  float xr0 = xr[(size_t)n * 2], xr1 = xr[(size_t)n * 2 + 1];
  float mh = -INFINITY, lh = 0.f, c0 = 0.f, c1 = 0.f;
  int p0 = off[n], p1 = off[n + 1];
  float2 rawn = make_float2(0.f, 0.f);
  if (p0 < p1) rawn = *(const float2*)(xl + (size_t)srcl[p0] * 2);
  for (int p = p0; p < p1; ++p) {
    float sl0 = rawn.x, sl1 = rawn.y;
    if (p + 1 < p1) rawn = *(const float2*)(xl + (size_t)srcl[p + 1] * 2);
    float t0 = sl0 + xr0; t0 = t0 > 0.f ? t0 : 0.2f * t0;
    float t1 = sl1 + xr1; t1 = t1 > 0.f ? t1 : 0.2f * t1;
    float lg = t0 * a0 + t1 * a1;
    float mn = fmaxf(mh, lg);
    float scl = __expf(mh - mn);
    float pe = __expf(lg - mn);
    lh = lh * scl + pe;
    c0 = c0 * scl + pe * sl0;
    c1 = c1 * scl + pe * sl1;
    mh = mn;
  }
  float inv = 1.f / lh;
  float v0 = c0 * inv + bias[0];
  float v1 = c1 * inv + bias[1];
  float mx = fmaxf(v0, v1);
  float ls = mx + logf(__expf(v0 - mx) + __expf(v1 - mx));
  out[(size_t)n * 2] = v0 - ls;
  out[(size_t)n * 2 + 1] = v1 - ls;
}

static inline int cdiv(int a, int b) { return (a + b - 1) / b; }

extern "C" void kernel_launch(void* const* d_in, const int* in_sizes, int n_in,
                              void* d_out, int out_size, void* d_ws, size_t ws_size,
                              hipStream_t stream) {
  (void)in_sizes; (void)n_in; (void)out_size; (void)ws_size;
  const float* bfeat = (const float*)d_in[0];
  const float* cfeat = (const float*)d_in[1];
  const int* bei = (const int*)d_in[2];
  const int* cei = (const int*)d_in[3];
  const int* b2c = (const int*)d_in[4];
  const float* c1_wl = (const float*)d_in[5];
  const float* c1_wr = (const float*)d_in[6];
  const float* c1_att = (const float*)d_in[7];
  const float* c1_b = (const float*)d_in[8];
  const float* c2_wl = (const float*)d_in[9];
  const float* c2_wr = (const float*)d_in[10];
  const float* c2_att = (const float*)d_in[11];
  const float* c2_b = (const float*)d_in[12];
  const float* fa_w1 = (const float*)d_in[13];
  const float* fa_b1 = (const float*)d_in[14];
  const float* fa_w2 = (const float*)d_in[15];
  const float* fa_b2 = (const float*)d_in[16];
  const float* b1_wl = (const float*)d_in[17];
  const float* b1_wr = (const float*)d_in[18];
  const float* b1_att = (const float*)d_in[19];
  const float* b1_b = (const float*)d_in[20];
  const float* b2_wl = (const float*)d_in[21];
  const float* b2_wr = (const float*)d_in[22];
  const float* b2_att = (const float*)d_in[23];
  const float* b2_b = (const float*)d_in[24];
  const float* b3_wl = (const float*)d_in[25];
  const float* b3_wr = (const float*)d_in[26];
  const float* b3_att = (const float*)d_in[27];
  const float* b3_b = (const float*)d_in[28];
  char* ws = (char*)d_ws;
  float* out = (float*)d_out;

  const int* b_src_arr = bei;
  const int* b_dst_arr = bei + EBU;
  const int* c_src_arr = cei;
  const int* c_dst_arr = cei + ECO;

  f16*   X1H  = (f16*)(ws + OFF_X1H);
  float* X2   = (float*)(ws + OFF_X2);
  f16*   XLH  = (f16*)(ws + OFF_XLH);
  f16*   XRH  = (f16*)(ws + OFF_XRH);
  f16*   XL2  = (f16*)(ws + OFF_XL2);
  f16*   XR2  = (f16*)(ws + OFF_XR2);
  f16*   CXLh = (f16*)(ws + OFF_CXL);
  f16*   CXRh = (f16*)(ws + OFF_CXR);
  f16*   CX1h = (f16*)(ws + OFF_CX1);
  f16*   CX2Lh= (f16*)(ws + OFF_CX2L);
  f16*   CX2Rh= (f16*)(ws + OFF_CX2R);
  f16*   BF16 = (f16*)(ws + OFF_BF16);
  f16*   CXF16= (f16*)(ws + OFF_CXF16);
  float* WM   = (float*)(ws + OFF_WM);
  float* XL3  = (float*)(ws + OFF_XL3);
  float* XR3  = (float*)(ws + OFF_XR3);
  f16*   FAW  = (f16*)(ws + OFF_FAW);
  f16*   B1LT = (f16*)(ws + OFF_B1LT);
  f16*   B1RT = (f16*)(ws + OFF_B1RT);
  f16*   B2T  = (f16*)(ws + OFF_B2T);
  f16*   C1T  = (f16*)(ws + OFF_C1T);
  f16*   C2T  = (f16*)(ws + OFF_C2T);
  f16*   CF16 = (f16*)(ws + OFF_CF16);
  int* BOFF = (int*)(ws + OFF_BOFF);
  int* BCUR = (int*)(ws + OFF_BCUR);
  int* BSRC = (int*)(ws + OFF_BSRC);
  int* COFF = (int*)(ws + OFF_COFF);
  int* CCUR = (int*)(ws + OFF_CCUR);
  int* CSRC = (int*)(ws + OFF_CSRC);
  int* SC1  = (int*)(ws + OFF_SC1);
  int* SC2  = (int*)(ws + OFF_SC2);
  int* SC1C = (int*)(ws + OFF_SC1C);
  int* SC2C = (int*)(ws + OFF_SC2C);

  // ---- weight + feature f16 pre-conversion (one launch for all 9 weights) ----
  k_cvtall<<<dim3(cdiv(192 * 512, 256), 16), 256, 0, stream>>>(
      fa_w1, b1_wl, b1_wr, b2_wl, b2_wr, c1_wl, c1_wr, c2_wl, c2_wr,
      FAW, B1LT, B1RT, B2T, C1T, C2T);
  k_cvt4<<<cdiv(NBLD * 16, 256), 256, 0, stream>>>(bfeat, BF16, NBLD * 16);
  k_cvt4<<<cdiv(NCOM * 8, 256), 256, 0, stream>>>(cfeat, CF16, NCOM * 8);

  // ---- CSR build (both graphs, merged stages) ----
  k_zero2<<<cdiv(NBLD + NCOM, 256), 256, 0, stream>>>(BCUR, NBLD, CCUR, NCOM);
  k_count2<<<cdiv(EBT + ECT, 256), 256, 0, stream>>>(b_dst_arr, c_dst_arr, BCUR, CCUR);
  k_scan1g<<<dim3(cdiv(NBLD, 2048), 2), 256, 0, stream>>>(BCUR, CCUR, BOFF, COFF, SC1, SC1C);
  k_scan2g<<<2, 256, 0, stream>>>(SC1, SC1C, cdiv(NBLD, 2048), cdiv(NCOM, 2048), SC2, SC2C);
  k_scan3c<<<cdiv(NBLD, 256), 256, 0, stream>>>(BOFF, NBLD, SC2, EBT, BCUR);
  k_scan3c<<<cdiv(NCOM, 256), 256, 0, stream>>>(COFF, NCOM, SC2C, ECT, CCUR);
  k_scatter2<<<cdiv(EBT + ECT, 256), 256, 0, stream>>>(
      b_src_arr, b_dst_arr, c_src_arr, c_dst_arr, BCUR, CCUR, BSRC, CSRC);

  // ---- community GNN (MFMA f16) ----
  {
    int pC = cdiv(cdiv(NCOM, 128), 8);     // 10
    k_mgemm_gen<8><<<8 * pC * 8, 256, 0, stream>>>(
        CF16, 32, C1T, 32, CXLh, CXRh, 512, 512, NCOM);
    k_convf<8, 8, true, f16, f16><<<cdiv(NCOM, 4), 256, 0, stream>>>(
        CXLh, CXRh, c1_att, c1_b, COFF, CSRC, CX1h, NCOM, 512, 512);
    k_mgemm_gen<2><<<8 * pC * 2, 256, 0, stream>>>(
        CX1h, 512, C2T, 512, CX2Lh, CX2Rh, 128, 128, NCOM);
    k_convf<2, 16, true, f16, f16><<<cdiv(NCOM, 4), 256, 0, stream>>>(
        CX2Lh, CX2Rh, c2_att, c2_b, COFF, CSRC, CXF16, NCOM, 128, 128);
  }

  // ---- feature-attention fusion (MFMA GEMM per head, XCD-swizzled) ----
  k_zerof<<<cdiv(NBLD * 2, 256), 256, 0, stream>>>(WM, NBLD * 2);
  {
    int panels = cdiv(NBLD, 128);          // 782
    int ppx = cdiv(panels, 8);             // 98
    k_mgemm_fa<<<64 * ppx, 256, 0, stream>>>(
        BF16, CXF16, b2c, FAW, fa_b1, fa_w2, fa_b2, WM, NBLD);
  }

  // ---- building conv1: head pairs (1 merged GEMM launch per pair) -> X1H f16 ----
  {
    int pB = cdiv(cdiv(NBLD, 128), 8);     // 98
    for (int cp = 0; cp < 4; ++cp) {
      k_mgemm_b1<<<16 * pB, 256, 0, stream>>>(
          BF16, CXF16, b2c, WM, B1LT, B1RT, cp * 128, XLH, XRH, NBLD);
      k_convf<2, 32, true, f16, f16><<<cdiv(NBLD, 4), 256, 0, stream>>>(
          XLH, XRH, b1_att + cp * 128, b1_b + cp * 128, BOFF, BSRC, X1H + cp * 128, NBLD, 128, 512);
    }
    // ---- b2: single K=512 MFMA GEMM -> XL2/XR2 f16 ----
    k_mgemm_gen<2><<<8 * pB * 2, 256, 0, stream>>>(
        X1H, 512, B2T, 512, XL2, XR2, 128, 128, NBLD);
  }

  // ---- building conv2 (f16 in, f32 out; X2 overlays dead X1H) ----
  k_convf<2, 16, true, f16, float><<<cdiv(NBLD, 4), 256, 0, stream>>>(
      XL2, XR2, b2_att, b2_b, BOFF, BSRC, X2, NBLD, 128, 128);

  // ---- conv3 + log_softmax ----
  k_b3gemm<<<cdiv(NBLD, 4), 256, 0, stream>>>(X2, b3_wl, b3_wr, XL3, XR3, NBLD);
  k_conv3<<<cdiv(NBLD, 256), 256, 0, stream>>>(XL3, XR3, b3_att, b3_b, BOFF, BSRC, out, NBLD);
}